// Round 1
// baseline (155.644 us; speedup 1.0000x reference)
//
#include <hip/hip_runtime.h>
#include <hip/hip_bf16.h>

// Live computation only (GNN layers are dead code in the reference):
//   hg[b] = [mean(h_comp|g==b), mean2(h_port|g==b), mean(h_net|g==b)]  -> [64,4]
//   out = relu(relu(hg@Wc1+bc1)@Wc2+bc2)@Wc3+bc3                        -> [64,10]

#define NGRAPH 64

// ws float layout:
// [0..63]    sum_comp[g]
// [64..127]  cnt_comp[g]
// [128..255] sum_port[g*2+f]
// [256..319] cnt_port[g]
// [320..383] sum_net[g]
// [384..447] cnt_net[g]

#define NB_COMP 128
#define NB_PORT 384
#define NB_NET  128

template <int NF>
__device__ void reduce_type(const float* __restrict__ h, const int* __restrict__ gid, int n,
                            float* __restrict__ gsum, float* __restrict__ gcnt,
                            int nblocks, int bid) {
    __shared__ float bins[NGRAPH][4];  // s0, s1, cnt, pad
    for (int i = threadIdx.x; i < NGRAPH * 4; i += blockDim.x) ((float*)bins)[i] = 0.f;
    __syncthreads();

    int per = (n + nblocks - 1) / nblocks;
    int start = bid * per;
    int end = min(n, start + per);

    int cur = -1;
    float s0 = 0.f, s1 = 0.f, cnt = 0.f;
    for (int i = start + (int)threadIdx.x; i < end; i += (int)blockDim.x) {
        int g = gid[i];
        if (g != cur) {
            if (cur >= 0) {
                atomicAdd(&bins[cur][0], s0);
                if (NF == 2) atomicAdd(&bins[cur][1], s1);
                atomicAdd(&bins[cur][2], cnt);
            }
            cur = g; s0 = 0.f; s1 = 0.f; cnt = 0.f;
        }
        if (NF == 1) {
            s0 += h[i];
        } else {
            float2 v = ((const float2*)h)[i];
            s0 += v.x; s1 += v.y;
        }
        cnt += 1.f;
    }
    if (cur >= 0) {
        atomicAdd(&bins[cur][0], s0);
        if (NF == 2) atomicAdd(&bins[cur][1], s1);
        atomicAdd(&bins[cur][2], cnt);
    }
    __syncthreads();

    for (int g = threadIdx.x; g < NGRAPH; g += blockDim.x) {
        float c = bins[g][2];
        if (c != 0.f) {
            if (NF == 1) {
                atomicAdd(&gsum[g], bins[g][0]);
            } else {
                atomicAdd(&gsum[g * 2 + 0], bins[g][0]);
                atomicAdd(&gsum[g * 2 + 1], bins[g][1]);
            }
            atomicAdd(&gcnt[g], c);
        }
    }
}

__global__ __launch_bounds__(256) void reduce_kernel(
    const float* __restrict__ h_comp, const float* __restrict__ h_port,
    const float* __restrict__ h_net,
    const int* __restrict__ gid_comp, const int* __restrict__ gid_port,
    const int* __restrict__ gid_net,
    int n_comp, int n_port, int n_net,
    float* __restrict__ ws) {
    int bid = blockIdx.x;
    if (bid < NB_COMP) {
        reduce_type<1>(h_comp, gid_comp, n_comp, ws + 0, ws + 64, NB_COMP, bid);
    } else if (bid < NB_COMP + NB_PORT) {
        reduce_type<2>(h_port, gid_port, n_port, ws + 128, ws + 256, NB_PORT, bid - NB_COMP);
    } else {
        reduce_type<1>(h_net, gid_net, n_net, ws + 320, ws + 384, NB_NET, bid - NB_COMP - NB_PORT);
    }
}

__global__ __launch_bounds__(256) void mlp_kernel(
    const float* __restrict__ ws,
    const float* __restrict__ Wc1, const float* __restrict__ bc1,
    const float* __restrict__ Wc2, const float* __restrict__ bc2,
    const float* __restrict__ Wc3, const float* __restrict__ bc3,
    float* __restrict__ out) {
    __shared__ float hg[NGRAPH][4];
    __shared__ float s1[NGRAPH][132];  // +4 pad vs 128 to break bank aliasing in layer 3
    __shared__ float s2[NGRAPH][132];

    int tid = threadIdx.x;

    if (tid < NGRAPH) {
        int g = tid;
        float cc = fmaxf(ws[64 + g], 1.f);
        hg[g][0] = ws[g] / cc;
        float cp = fmaxf(ws[256 + g], 1.f);
        hg[g][1] = ws[128 + g * 2 + 0] / cp;
        hg[g][2] = ws[128 + g * 2 + 1] / cp;
        float cn = fmaxf(ws[384 + g], 1.f);
        hg[g][3] = ws[320 + g] / cn;
    }
    __syncthreads();

    int j = tid & 127;
    int half = tid >> 7;  // 0 or 1; each thread handles rows {half, half+2, ...}

    // Layer 1: [64,4] @ [4,128]
    float w0 = Wc1[0 * 128 + j];
    float w1 = Wc1[1 * 128 + j];
    float w2 = Wc1[2 * 128 + j];
    float w3 = Wc1[3 * 128 + j];
    float bb1 = bc1[j];
    for (int i = 0; i < 32; ++i) {
        int b = half + 2 * i;
        float v = hg[b][0] * w0 + hg[b][1] * w1 + hg[b][2] * w2 + hg[b][3] * w3 + bb1;
        s1[b][j] = fmaxf(v, 0.f);
    }
    __syncthreads();

    // Layer 2: [64,128] @ [128,128]
    float acc[32];
    float bb2 = bc2[j];
#pragma unroll
    for (int i = 0; i < 32; ++i) acc[i] = bb2;
    for (int k = 0; k < 128; ++k) {
        float w = Wc2[k * 128 + j];  // coalesced across 128 lanes
#pragma unroll
        for (int i = 0; i < 32; ++i) acc[i] += s1[half + 2 * i][k] * w;  // LDS broadcast
    }
#pragma unroll
    for (int i = 0; i < 32; ++i) s2[half + 2 * i][j] = fmaxf(acc[i], 0.f);
    __syncthreads();

    // Layer 3: [64,128] @ [128,10] -> 640 outputs
    for (int o = tid; o < NGRAPH * 10; o += 256) {
        int b = o / 10;
        int c = o - b * 10;
        float a = bc3[c];
        for (int k = 0; k < 128; ++k) a += s2[b][k] * Wc3[k * 10 + c];
        out[o] = a;
    }
}

extern "C" void kernel_launch(void* const* d_in, const int* in_sizes, int n_in,
                              void* d_out, int out_size, void* d_ws, size_t ws_size,
                              hipStream_t stream) {
    const float* h_comp = (const float*)d_in[0];
    const float* h_port = (const float*)d_in[1];
    const float* h_net  = (const float*)d_in[2];
    // d_in[3..6]: edge arrays — dead code in the reference, unused.
    const int* gid_comp = (const int*)d_in[7];
    const int* gid_port = (const int*)d_in[8];
    const int* gid_net  = (const int*)d_in[9];
    // d_in[10..21]: GraphConv weights — dead code, unused.
    const float* Wc1 = (const float*)d_in[22];
    const float* bc1 = (const float*)d_in[23];
    const float* Wc2 = (const float*)d_in[24];
    const float* bc2 = (const float*)d_in[25];
    const float* Wc3 = (const float*)d_in[26];
    const float* bc3 = (const float*)d_in[27];

    int n_comp = in_sizes[0];       // 100000 (dim 1)
    int n_port = in_sizes[1] / 2;   // 400000 (dim 2)
    int n_net  = in_sizes[2];       // 150000 (dim 1)

    float* ws = (float*)d_ws;
    float* out = (float*)d_out;

    hipMemsetAsync(ws, 0, 448 * sizeof(float), stream);

    reduce_kernel<<<NB_COMP + NB_PORT + NB_NET, 256, 0, stream>>>(
        h_comp, h_port, h_net, gid_comp, gid_port, gid_net,
        n_comp, n_port, n_net, ws);

    mlp_kernel<<<1, 256, 0, stream>>>(ws, Wc1, bc1, Wc2, bc2, Wc3, bc3, out);
}

// Round 2
// 122.908 us; speedup vs baseline: 1.2663x; 1.2663x over previous
//
#include <hip/hip_runtime.h>
#include <hip/hip_bf16.h>

// Live computation only (GNN layers are dead code in the reference):
//   hg[b] = [mean(h_comp|g==b), mean2(h_port|g==b), mean(h_net|g==b)]  -> [64,4]
//   out = relu(relu(hg@Wc1+bc1)@Wc2+bc2)@Wc3+bc3                        -> [64,10]

#define NGRAPH 64

// ws float layout:
// [0..63]    sum_comp[g]
// [64..127]  cnt_comp[g]
// [128..255] sum_port[g*2+f]
// [256..319] cnt_port[g]
// [320..383] sum_net[g]
// [384..447] cnt_net[g]

#define NB_COMP 128
#define NB_PORT 384
#define NB_NET  128

template <int NF>
__device__ void reduce_type(const float* __restrict__ h, const int* __restrict__ gid, int n,
                            float* __restrict__ gsum, float* __restrict__ gcnt,
                            int nblocks, int bid) {
    __shared__ float bins[NGRAPH][4];  // s0, s1, cnt, pad
    for (int i = threadIdx.x; i < NGRAPH * 4; i += blockDim.x) ((float*)bins)[i] = 0.f;
    __syncthreads();

    int nv = (n + 3) >> 2;  // vec4 groups
    int per = (nv + nblocks - 1) / nblocks;
    int start = bid * per;
    int end = min(nv, start + per);

    int cur = -1;
    float s0 = 0.f, s1 = 0.f, cnt = 0.f;

    for (int iv = start + (int)threadIdx.x; iv < end; iv += (int)blockDim.x) {
        int i = iv * 4;
        int g[4];
        float v0[4], v1[4];
        if (i + 3 < n) {
            int4 g4 = ((const int4*)gid)[iv];
            g[0] = g4.x; g[1] = g4.y; g[2] = g4.z; g[3] = g4.w;
            if (NF == 1) {
                float4 hv = ((const float4*)h)[iv];
                v0[0] = hv.x; v0[1] = hv.y; v0[2] = hv.z; v0[3] = hv.w;
            } else {
                float4 ha = ((const float4*)h)[iv * 2];
                float4 hb = ((const float4*)h)[iv * 2 + 1];
                v0[0] = ha.x; v1[0] = ha.y; v0[1] = ha.z; v1[1] = ha.w;
                v0[2] = hb.x; v1[2] = hb.y; v0[3] = hb.z; v1[3] = hb.w;
            }
        } else {
#pragma unroll
            for (int t = 0; t < 4; ++t) {
                if (i + t < n) {
                    g[t] = gid[i + t];
                    if (NF == 1) { v0[t] = h[i + t]; }
                    else { v0[t] = h[(i + t) * 2]; v1[t] = h[(i + t) * 2 + 1]; }
                } else {
                    g[t] = -2;  // sentinel: skip
                    v0[t] = 0.f; v1[t] = 0.f;
                }
            }
        }
#pragma unroll
        for (int t = 0; t < 4; ++t) {
            if (g[t] == -2) continue;
            if (g[t] != cur) {
                if (cur >= 0) {
                    atomicAdd(&bins[cur][0], s0);
                    if (NF == 2) atomicAdd(&bins[cur][1], s1);
                    atomicAdd(&bins[cur][2], cnt);
                }
                cur = g[t]; s0 = 0.f; s1 = 0.f; cnt = 0.f;
            }
            s0 += v0[t];
            if (NF == 2) s1 += v1[t];
            cnt += 1.f;
        }
    }
    if (cur >= 0) {
        atomicAdd(&bins[cur][0], s0);
        if (NF == 2) atomicAdd(&bins[cur][1], s1);
        atomicAdd(&bins[cur][2], cnt);
    }
    __syncthreads();

    for (int g = threadIdx.x; g < NGRAPH; g += blockDim.x) {
        float c = bins[g][2];
        if (c != 0.f) {
            if (NF == 1) {
                atomicAdd(&gsum[g], bins[g][0]);
            } else {
                atomicAdd(&gsum[g * 2 + 0], bins[g][0]);
                atomicAdd(&gsum[g * 2 + 1], bins[g][1]);
            }
            atomicAdd(&gcnt[g], c);
        }
    }
}

__global__ __launch_bounds__(256) void reduce_kernel(
    const float* __restrict__ h_comp, const float* __restrict__ h_port,
    const float* __restrict__ h_net,
    const int* __restrict__ gid_comp, const int* __restrict__ gid_port,
    const int* __restrict__ gid_net,
    int n_comp, int n_port, int n_net,
    float* __restrict__ ws) {
    int bid = blockIdx.x;
    if (bid < NB_COMP) {
        reduce_type<1>(h_comp, gid_comp, n_comp, ws + 0, ws + 64, NB_COMP, bid);
    } else if (bid < NB_COMP + NB_PORT) {
        reduce_type<2>(h_port, gid_port, n_port, ws + 128, ws + 256, NB_PORT, bid - NB_COMP);
    } else {
        reduce_type<1>(h_net, gid_net, n_net, ws + 320, ws + 384, NB_NET, bid - NB_COMP - NB_PORT);
    }
}

// One block per graph (64 blocks x 128 threads). Each block runs the whole MLP
// for its row: work per block is tiny; parallelism across 64 CUs removes the
// single-CU instruction-issue serialization seen in R1 (47us -> ~4us).
__global__ __launch_bounds__(128) void mlp_kernel(
    const float* __restrict__ ws,
    const float* __restrict__ Wc1, const float* __restrict__ bc1,
    const float* __restrict__ Wc2, const float* __restrict__ bc2,
    const float* __restrict__ Wc3, const float* __restrict__ bc3,
    float* __restrict__ out) {
    __shared__ float h1[128];
    __shared__ float h2[128];

    int b = blockIdx.x;   // graph
    int j = threadIdx.x;  // column

    // hg for this graph (every thread computes the same 4 scalars; cheap)
    float cc = fmaxf(ws[64 + b], 1.f);
    float g0 = ws[b] / cc;
    float cp = fmaxf(ws[256 + b], 1.f);
    float g1 = ws[128 + 2 * b] / cp;
    float g2 = ws[128 + 2 * b + 1] / cp;
    float cn = fmaxf(ws[384 + b], 1.f);
    float g3 = ws[320 + b] / cn;

    // Layer 1: [4] @ [4,128]
    float v = g0 * Wc1[j] + g1 * Wc1[128 + j] + g2 * Wc1[256 + j] + g3 * Wc1[384 + j] + bc1[j];
    h1[j] = fmaxf(v, 0.f);
    __syncthreads();

    // Layer 2: [128] @ [128,128]; h1 via ds_read_b128 broadcast, Wc2 coalesced (L2-hot)
    float acc = bc2[j];
#pragma unroll 8
    for (int k = 0; k < 128; k += 4) {
        float4 hh = *(const float4*)&h1[k];
        float w0 = Wc2[(k + 0) * 128 + j];
        float w1 = Wc2[(k + 1) * 128 + j];
        float w2 = Wc2[(k + 2) * 128 + j];
        float w3 = Wc2[(k + 3) * 128 + j];
        acc += hh.x * w0 + hh.y * w1 + hh.z * w2 + hh.w * w3;
    }
    h2[j] = fmaxf(acc, 0.f);
    __syncthreads();

    // Layer 3: [128] @ [128,10] — 10 threads, full dots from LDS (broadcast reads)
    if (j < 10) {
        float a = bc3[j];
#pragma unroll 8
        for (int k = 0; k < 128; ++k) a += h2[k] * Wc3[k * 10 + j];
        out[b * 10 + j] = a;
    }
}

extern "C" void kernel_launch(void* const* d_in, const int* in_sizes, int n_in,
                              void* d_out, int out_size, void* d_ws, size_t ws_size,
                              hipStream_t stream) {
    const float* h_comp = (const float*)d_in[0];
    const float* h_port = (const float*)d_in[1];
    const float* h_net  = (const float*)d_in[2];
    // d_in[3..6]: edge arrays — dead code in the reference, unused.
    const int* gid_comp = (const int*)d_in[7];
    const int* gid_port = (const int*)d_in[8];
    const int* gid_net  = (const int*)d_in[9];
    // d_in[10..21]: GraphConv weights — dead code, unused.
    const float* Wc1 = (const float*)d_in[22];
    const float* bc1 = (const float*)d_in[23];
    const float* Wc2 = (const float*)d_in[24];
    const float* bc2 = (const float*)d_in[25];
    const float* Wc3 = (const float*)d_in[26];
    const float* bc3 = (const float*)d_in[27];

    int n_comp = in_sizes[0];       // 100000 (dim 1)
    int n_port = in_sizes[1] / 2;   // 400000 (dim 2)
    int n_net  = in_sizes[2];       // 150000 (dim 1)

    float* ws = (float*)d_ws;
    float* out = (float*)d_out;

    hipMemsetAsync(ws, 0, 448 * sizeof(float), stream);

    reduce_kernel<<<NB_COMP + NB_PORT + NB_NET, 256, 0, stream>>>(
        h_comp, h_port, h_net, gid_comp, gid_port, gid_net,
        n_comp, n_port, n_net, ws);

    mlp_kernel<<<NGRAPH, 128, 0, stream>>>(ws, Wc1, bc1, Wc2, bc2, Wc3, bc3, out);
}